// Round 3
// baseline (969.157 us; speedup 1.0000x reference)
//
#include <hip/hip_runtime.h>
#include <math.h>

// VQ nearest-codebook, v4: occupancy-first restructure.
//
// History: v1 754us (MfmaUtil 13, VALU 25, 3.3e7 bank-conflict cycles) ->
// v3 697us (VALU 12.9, conflicts 8e4, FETCH halved -- but dur FLAT and
// MfmaUtil still 12%). Conclusion: never VALU-bound; latency-bound with only
// 4-8 waves/CU resident (64 KiB LDS -> 2 blocks/CU, 248 VGPR -> 2 waves/SIMD).
// Roofline row: both pipes low + occupancy low -> more waves, smaller tiles.
//
// v4: BM=32 points/block -> 32 KiB LDS; acc 2x4 (32 VGPR), 8 top-2 slots,
// single-buffered B; __launch_bounds__(256,3) caps VGPR at 170 ->
// 3 blocks/CU = 12 waves/CU (3x v3). Numerics byte-identical to v3:
// 3-pass split-bf16 MFMA (hh+lh+hl), per-lane top-2, ln-butterfly,
// 4-wave merge, exact fp32 recheck, gather. Codebook bf16 planes in d_ws
// (guarded; template fallback if ws too small). L2 B-traffic at BM=32 is
// 4 GB -> ~16 TB/s at the predicted 250us, under the 34.5 TB/s L2 ceiling.

typedef __attribute__((ext_vector_type(8))) short short8;   // 8 bf16 = 4 VGPR
typedef __attribute__((ext_vector_type(4))) float f32x4;

#define C_DIM 256
#define BM 32     // points per block
#define KT 256    // codes per kt tile (4 tiles cover K=1024)

__device__ __forceinline__ unsigned short f2bf(float f) {
    unsigned u = __float_as_uint(f);
    return (unsigned short)((u + 0x7fffu + ((u >> 16) & 1u)) >> 16);
}

// cb (K x 256 fp32) -> exact e2, and (if PLANES) bf16 hi/lo planes.
template <bool PLANES>
__global__ __launch_bounds__(256) void vq_prep(
    const float* __restrict__ cb, unsigned short* __restrict__ cbh,
    unsigned short* __restrict__ cbl, float* __restrict__ e2, int K) {
    int wave = threadIdx.x >> 6;
    int lane = threadIdx.x & 63;
    int code = blockIdx.x * 4 + wave;
    if (code >= K) return;
    float4 v = ((const float4*)(cb + (size_t)code * C_DIM))[lane];
    if constexpr (PLANES) {
        unsigned short h[4], l[4];
#pragma unroll
        for (int i = 0; i < 4; ++i) {
            float f = ((const float*)&v)[i];
            unsigned short hh = f2bf(f);
            h[i] = hh;
            l[i] = f2bf(f - __uint_as_float((unsigned)hh << 16));
        }
        *(ushort4*)(cbh + (size_t)code * C_DIM + lane * 4) = make_ushort4(h[0], h[1], h[2], h[3]);
        *(ushort4*)(cbl + (size_t)code * C_DIM + lane * 4) = make_ushort4(l[0], l[1], l[2], l[3]);
    }
    float s = v.x * v.x + v.y * v.y + v.z * v.z + v.w * v.w;
#pragma unroll
    for (int off = 32; off > 0; off >>= 1) s += __shfl_down(s, off, 64);
    if (lane == 0) e2[code] = s;
}

// A fragments (2 m-tiles) from swizzled LDS.
#define LOADA(KS)                                                    \
    {                                                                \
        const int o_ = (KS) * 4 + q;                                 \
        _Pragma("unroll")                                            \
        for (int mt = 0; mt < 2; ++mt) {                             \
            const int ga_ = (o_ ^ swA[mt]) * 8;                      \
            Ah[mt] = *(const short8*)(sXh + arow[mt] + ga_);         \
            Al[mt] = *(const short8*)(sXl + arow[mt] + ga_);         \
        }                                                            \
    }

// B fragments: bf16 planes (PLANES) or fp32 cb + in-register split (!PLANES).
#define LOADB(KS)                                                              \
    {                                                                          \
        _Pragma("unroll")                                                      \
        for (int nt = 0; nt < 4; ++nt) {                                       \
            if constexpr (PLANES) {                                            \
                Bh[nt] = *(const short8*)(bhp + nt * 16 * C_DIM + (KS) * 32);  \
                Bl[nt] = *(const short8*)(blp + nt * 16 * C_DIM + (KS) * 32);  \
            } else {                                                           \
                const float* cp_ = cbf + (size_t)nt * 16 * C_DIM + (KS) * 32;  \
                float4 b0_ = ((const float4*)cp_)[0];                          \
                float4 b1_ = ((const float4*)cp_)[1];                          \
                short8 bh_, bl_;                                               \
                _Pragma("unroll")                                              \
                for (int i = 0; i < 8; ++i) {                                  \
                    float f_ = (i < 4) ? ((const float*)&b0_)[i]               \
                                       : ((const float*)&b1_)[i - 4];          \
                    unsigned short hh_ = f2bf(f_);                             \
                    bh_[i] = (short)hh_;                                       \
                    bl_[i] = (short)f2bf(f_ - __uint_as_float((unsigned)hh_ << 16)); \
                }                                                              \
                Bh[nt] = bh_;                                                  \
                Bl[nt] = bl_;                                                  \
            }                                                                  \
        }                                                                      \
    }

template <bool PLANES>
__global__ __launch_bounds__(256, 3) void vq_main(
    const float* __restrict__ x, const float* __restrict__ cb,
    const unsigned short* __restrict__ cbh, const unsigned short* __restrict__ cbl,
    const float* __restrict__ e2, float* __restrict__ zq, float* __restrict__ idxf,
    int K) {

    __shared__ char smem[32768];
    short* sXh = (short*)smem;             // [32][256] bf16 hi, granule-swizzled
    short* sXl = (short*)(smem + 16384);   // [32][256] bf16 lo

    const int tid = threadIdx.x;
    const int lane = tid & 63;
    const int w = tid >> 6;          // wave id 0..3
    const int ln = lane & 15;        // column-within-16 (code select)
    const int q = lane >> 4;         // k-octet / point-quad select
    const int wn = w * 64;           // wave's code-column offset in KT tile
    const size_t basep = (size_t)blockIdx.x * BM;

    // ---- split the x tile into LDS once (XOR-swizzled 16B granules) ----
#pragma unroll
    for (int j = 0; j < 4; ++j) {
        int gi = j * 256 + tid;        // granule id: 32 rows x 32 granules
        int p = gi >> 5, g = gi & 31;
        const float4* src = (const float4*)(x + (basep + p) * C_DIM + g * 8);
        float4 a0 = src[0], a1 = src[1];
        short8 hi, lo;
#pragma unroll
        for (int i = 0; i < 8; ++i) {
            float f = (i < 4) ? ((const float*)&a0)[i] : ((const float*)&a1)[i - 4];
            unsigned short hh = f2bf(f);
            hi[i] = (short)hh;
            lo[i] = (short)f2bf(f - __uint_as_float((unsigned)hh << 16));
        }
        int dst = p * C_DIM + ((g ^ p) * 8);   // p in 0..31
        *(short8*)(sXh + dst) = hi;
        *(short8*)(sXl + dst) = lo;
    }
    __syncthreads();

    int arow[2], swA[2];
#pragma unroll
    for (int mt = 0; mt < 2; ++mt) {
        int R = mt * 16 + ln;
        arow[mt] = R * C_DIM;
        swA[mt] = R & 31;
    }

    // per-lane top-2 state for 8 point-slots
    float d1s[8], d2s[8];
    int c1s[8], c2s[8];
#pragma unroll
    for (int s = 0; s < 8; ++s) { d1s[s] = 1e30f; d2s[s] = 1e30f; c1s[s] = 0; c2s[s] = 1; }

    const int nkt = K / KT;
    for (int kt = 0; kt < nkt; ++kt) {
        f32x4 acc[2][4];
#pragma unroll
        for (int mt = 0; mt < 2; ++mt)
#pragma unroll
            for (int nt = 0; nt < 4; ++nt)
#pragma unroll
                for (int r = 0; r < 4; ++r) acc[mt][nt][r] = 0.0f;

        int cnv[4];
        float e2v[4];
#pragma unroll
        for (int nt = 0; nt < 4; ++nt) {
            cnv[nt] = kt * KT + wn + nt * 16 + ln;
            e2v[nt] = e2[cnv[nt]];
        }

        const unsigned short* bhp = cbh + ((size_t)kt * KT + wn + ln) * C_DIM + q * 8;
        const unsigned short* blp = cbl + ((size_t)kt * KT + wn + ln) * C_DIM + q * 8;
        const float* cbf = cb + ((size_t)kt * KT + wn + ln) * C_DIM + q * 8;

#pragma unroll
        for (int ks = 0; ks < 8; ++ks) {
            short8 Bh[4], Bl[4];
            LOADB(ks)
            short8 Ah[2], Al[2];
            LOADA(ks)
#pragma unroll
            for (int mt = 0; mt < 2; ++mt)
#pragma unroll
                for (int nt = 0; nt < 4; ++nt)
                    acc[mt][nt] = __builtin_amdgcn_mfma_f32_16x16x32_bf16(Ah[mt], Bh[nt], acc[mt][nt], 0, 0, 0);
#pragma unroll
            for (int mt = 0; mt < 2; ++mt)
#pragma unroll
                for (int nt = 0; nt < 4; ++nt)
                    acc[mt][nt] = __builtin_amdgcn_mfma_f32_16x16x32_bf16(Al[mt], Bh[nt], acc[mt][nt], 0, 0, 0);
#pragma unroll
            for (int mt = 0; mt < 2; ++mt)
#pragma unroll
                for (int nt = 0; nt < 4; ++nt)
                    acc[mt][nt] = __builtin_amdgcn_mfma_f32_16x16x32_bf16(Ah[mt], Bl[nt], acc[mt][nt], 0, 0, 0);
        }

        // ---- per-kt top-2 update (branchless) ----
#pragma unroll
        for (int mt = 0; mt < 2; ++mt)
#pragma unroll
            for (int nt = 0; nt < 4; ++nt)
#pragma unroll
                for (int r = 0; r < 4; ++r) {
                    float d = fmaf(-2.0f, acc[mt][nt][r], e2v[nt]);
                    int s = mt * 4 + r;
                    int cn = cnv[nt];
                    bool lt2 = d < d2s[s];
                    bool lt1 = d < d1s[s];
                    float td = lt1 ? d1s[s] : d;
                    int tc = lt1 ? c1s[s] : cn;
                    d2s[s] = lt2 ? td : d2s[s];
                    c2s[s] = lt2 ? tc : c2s[s];
                    d1s[s] = lt1 ? d : d1s[s];
                    c1s[s] = lt1 ? cn : c1s[s];
                }
    }

    // ---- butterfly top-2 merge across the 16 ln-lanes (codes disjoint) ----
#pragma unroll
    for (int m = 1; m <= 8; m <<= 1) {
#pragma unroll
        for (int s = 0; s < 8; ++s) {
            float od1 = __shfl_xor(d1s[s], m);
            int oc1 = __shfl_xor(c1s[s], m);
            float od2 = __shfl_xor(d2s[s], m);
            int oc2 = __shfl_xor(c2s[s], m);
            bool t = (od1 < d1s[s]) || (od1 == d1s[s] && oc1 < c1s[s]);
            float hd = t ? d1s[s] : od1;   // loser of firsts
            int hc = t ? c1s[s] : oc1;
            float nd1 = t ? od1 : d1s[s];
            int nc1 = t ? oc1 : c1s[s];
            bool u = od2 < d2s[s];
            float md = u ? od2 : d2s[s];   // min of seconds
            int mc = u ? oc2 : c2s[s];
            bool v2 = (hd < md) || (hd == md && hc < mc);
            d2s[s] = v2 ? hd : md;
            c2s[s] = v2 ? hc : mc;
            d1s[s] = nd1;
            c1s[s] = nc1;
        }
    }

    __syncthreads();   // all LDS x-tile reads done; safe to reuse
    float* mD1 = (float*)smem;              // [32][4]
    int* mC1 = (int*)(smem + 512);
    float* mD2 = (float*)(smem + 1024);
    int* mC2 = (int*)(smem + 1536);
    int* sCand = (int*)(smem + 2048);       // [32][2]
    int* sWin = (int*)(smem + 2304);        // [32]

    if (ln == 0) {
#pragma unroll
        for (int mt = 0; mt < 2; ++mt)
#pragma unroll
            for (int r = 0; r < 4; ++r) {
                int s = mt * 4 + r;
                int p = mt * 16 + q * 4 + r;
                mD1[p * 4 + w] = d1s[s];
                mC1[p * 4 + w] = c1s[s];
                mD2[p * 4 + w] = d2s[s];
                mC2[p * 4 + w] = c2s[s];
            }
    }
    __syncthreads();

    // ---- per-point merge of the 4 wave code-slices -> 2 candidates ----
    if (tid < BM) {
        int p = tid;
        float bd = mD1[p * 4];
        int bc = mC1[p * 4];
        int bw = 0;
#pragma unroll
        for (int ww = 1; ww < 4; ++ww) {
            float d = mD1[p * 4 + ww];
            int c = mC1[p * 4 + ww];
            bool t = (d < bd) || (d == bd && c < bc);
            bd = t ? d : bd;
            bc = t ? c : bc;
            bw = t ? ww : bw;
        }
        float sd = mD2[p * 4 + bw];
        int sc = mC2[p * 4 + bw];
#pragma unroll
        for (int ww = 0; ww < 4; ++ww) {
            if (ww == bw) continue;   // LDS-indexed, runtime bw is fine
            float d = mD1[p * 4 + ww];
            int c = mC1[p * 4 + ww];
            bool t = (d < sd) || (d == sd && c < sc);
            sd = t ? d : sd;
            sc = t ? c : sc;
        }
        sCand[p * 2] = bc;
        sCand[p * 2 + 1] = sc;
    }
    __syncthreads();

    // ---- exact fp32 recheck: one thread per (point, candidate) ----
    if (tid < 2 * BM) {
        int p = tid >> 1;
        int cc = sCand[tid];
        const float4* xr4 = (const float4*)(x + (basep + p) * C_DIM);
        const float4* cr4 = (const float4*)(cb + (size_t)cc * C_DIM);
        float4 s4 = {0.f, 0.f, 0.f, 0.f};
#pragma unroll 8
        for (int j = 0; j < 64; ++j) {
            float4 a = xr4[j], b = cr4[j];
            s4.x = fmaf(a.x, b.x, s4.x);
            s4.y = fmaf(a.y, b.y, s4.y);
            s4.z = fmaf(a.z, b.z, s4.z);
            s4.w = fmaf(a.w, b.w, s4.w);
        }
        float dot = (s4.x + s4.y) + (s4.z + s4.w);
        float d = fmaf(-2.0f, dot, e2[cc]);
        float od = __shfl_xor(d, 1);
        int oc = __shfl_xor(cc, 1);
        int winc = (d < od || (d == od && cc < oc)) ? cc : oc;
        if ((tid & 1) == 0) {
            sWin[p] = winc;
            idxf[basep + p] = (float)winc;
        }
    }
    __syncthreads();

    // ---- gather winning codebook rows -> zq (cb is L2-hot) ----
#pragma unroll 2
    for (int p = w * 8; p < w * 8 + 8; ++p) {
        int cc = sWin[p];
        float4 v = ((const float4*)(cb + (size_t)cc * C_DIM))[lane];
        ((float4*)(zq + (basep + p) * C_DIM))[lane] = v;
    }
}

extern "C" void kernel_launch(void* const* d_in, const int* in_sizes, int n_in,
                              void* d_out, int out_size, void* d_ws, size_t ws_size,
                              hipStream_t stream) {
    const float* x = (const float*)d_in[0];
    const float* cb = (const float*)d_in[1];
    int N = in_sizes[0] / C_DIM;   // 131072
    int K = in_sizes[1] / C_DIM;   // 1024

    float* zq = (float*)d_out;
    float* idxf = zq + (size_t)N * C_DIM;

    // workspace: e2 (4 KiB, always) + cbh/cbl planes (1 MiB, only if it fits)
    float* e2 = (float*)d_ws;
    unsigned short* cbh = (unsigned short*)((char*)d_ws + 4096);
    unsigned short* cbl = cbh + (size_t)K * C_DIM;
    size_t need = 4096 + (size_t)K * C_DIM * 2 * sizeof(unsigned short);

    if (ws_size >= need) {
        vq_prep<true><<<dim3((K + 3) / 4), dim3(256), 0, stream>>>(cb, cbh, cbl, e2, K);
        vq_main<true><<<dim3(N / BM), dim3(256), 0, stream>>>(x, cb, cbh, cbl, e2, zq, idxf, K);
    } else {
        vq_prep<false><<<dim3((K + 3) / 4), dim3(256), 0, stream>>>(cb, cbh, cbl, e2, K);
        vq_main<false><<<dim3(N / BM), dim3(256), 0, stream>>>(x, cb, cbh, cbl, e2, zq, idxf, K);
    }
}

// Round 4
// 712.136 us; speedup vs baseline: 1.3609x; 1.3609x over previous
//
#include <hip/hip_runtime.h>
#include <math.h>

// VQ nearest-codebook, v5: register-pressure fix so B prefetch pipelines.
//
// History: v1 754 (staging+VALU theory), v3 697 (conversion removed, conflicts
// ~0 -- flat), v4 855 (occupancy 31.6% -- WORSE, FETCH 702MB L2 thrash).
// All pipes ~10-15% in every variant => loads latency-SERIALIZED, not
// pipelined. Evidence: v3 VGPR=248 (at cap => dest-reg reuse => vmcnt(0)
// between loads), v4 VGPR=84 (launch_bounds-squeezed, same). 16 serialized
// ~400cyc loads/ks ~= 6-7K cyc closes the 8x stall gap in both.
//
// v5: mt=2/nt=4 per wave (acc 32 VGPR, top2 32), named B double-buffer
// (compile-time indexed), kt/ksp loops ROLLED (body ~500 instr), target
// ~180 VGPR under __launch_bounds__(256,2) => compiler can pipeline the
// 8 B-loads one ks ahead. BM=64 (2048 blocks: planes stay L2-resident,
// proven by v3's FETCH=153MB). A hi/lo split once into XOR-swizzled LDS
// (proven ~0 conflicts). Barrier-free main loop. Numerics: same per-cell
// accumulation order (ks 0..7 x hh,lh,hl per 128-code tile), top-2 +
// exact fp32 recheck decides => absmax 0 class preserved.

typedef __attribute__((ext_vector_type(8))) short short8;   // 8 bf16 = 4 VGPR
typedef __attribute__((ext_vector_type(4))) float f32x4;

#define C_DIM 256
#define BM 64     // points per block
#define KT 128    // codes per kt tile (8 tiles cover K=1024)

__device__ __forceinline__ unsigned short f2bf(float f) {
    unsigned u = __float_as_uint(f);
    return (unsigned short)((u + 0x7fffu + ((u >> 16) & 1u)) >> 16);
}

// cb (K x 256 fp32) -> exact e2, and (if PLANES) bf16 hi/lo planes.
template <bool PLANES>
__global__ __launch_bounds__(256) void vq_prep(
    const float* __restrict__ cb, unsigned short* __restrict__ cbh,
    unsigned short* __restrict__ cbl, float* __restrict__ e2, int K) {
    int wave = threadIdx.x >> 6;
    int lane = threadIdx.x & 63;
    int code = blockIdx.x * 4 + wave;
    if (code >= K) return;
    float4 v = ((const float4*)(cb + (size_t)code * C_DIM))[lane];
    if constexpr (PLANES) {
        unsigned short h[4], l[4];
#pragma unroll
        for (int i = 0; i < 4; ++i) {
            float f = ((const float*)&v)[i];
            unsigned short hh = f2bf(f);
            h[i] = hh;
            l[i] = f2bf(f - __uint_as_float((unsigned)hh << 16));
        }
        *(ushort4*)(cbh + (size_t)code * C_DIM + lane * 4) = make_ushort4(h[0], h[1], h[2], h[3]);
        *(ushort4*)(cbl + (size_t)code * C_DIM + lane * 4) = make_ushort4(l[0], l[1], l[2], l[3]);
    }
    float s = v.x * v.x + v.y * v.y + v.z * v.z + v.w * v.w;
#pragma unroll
    for (int off = 32; off > 0; off >>= 1) s += __shfl_down(s, off, 64);
    if (lane == 0) e2[code] = s;
}

// A fragments (2 m-tiles) from swizzled LDS, k-step KS.
#define LOADA(KS)                                                    \
    {                                                                \
        const int o_ = (KS) * 4 + q;                                 \
        _Pragma("unroll")                                            \
        for (int mt = 0; mt < 2; ++mt) {                             \
            const int ga_ = ((o_ ^ swA[mt]) * 8);                    \
            Ah[mt] = *(const short8*)(sXh + arow[mt] + ga_);         \
            Al[mt] = *(const short8*)(sXl + arow[mt] + ga_);         \
        }                                                            \
    }

// B fragments into named buffers DH/DL (compile-time identity), k-step KS.
#define LOADB(DH, DL, KS)                                                      \
    {                                                                          \
        _Pragma("unroll")                                                      \
        for (int nt = 0; nt < 4; ++nt) {                                       \
            if constexpr (PLANES) {                                            \
                DH[nt] = *(const short8*)(bhp + nt * 16 * C_DIM + (KS) * 32);  \
                DL[nt] = *(const short8*)(blp + nt * 16 * C_DIM + (KS) * 32);  \
            } else {                                                           \
                const float* cp_ = cbf + (size_t)nt * 16 * C_DIM + (KS) * 32;  \
                float4 b0_ = ((const float4*)cp_)[0];                          \
                float4 b1_ = ((const float4*)cp_)[1];                          \
                short8 bh_, bl_;                                               \
                _Pragma("unroll")                                              \
                for (int i = 0; i < 8; ++i) {                                  \
                    float f_ = (i < 4) ? ((const float*)&b0_)[i]               \
                                       : ((const float*)&b1_)[i - 4];          \
                    unsigned short hh_ = f2bf(f_);                             \
                    bh_[i] = (short)hh_;                                       \
                    bl_[i] = (short)f2bf(f_ - __uint_as_float((unsigned)hh_ << 16)); \
                }                                                              \
                DH[nt] = bh_;                                                  \
                DL[nt] = bl_;                                                  \
            }                                                                  \
        }                                                                      \
    }

// 3-pass MFMA cluster on (Ah,Al) x (BH,BL).
#define MFMA3(BH, BL)                                                          \
    {                                                                          \
        _Pragma("unroll")                                                      \
        for (int mt = 0; mt < 2; ++mt)                                         \
            _Pragma("unroll")                                                  \
            for (int nt = 0; nt < 4; ++nt)                                     \
                acc[mt][nt] = __builtin_amdgcn_mfma_f32_16x16x32_bf16(Ah[mt], BH[nt], acc[mt][nt], 0, 0, 0); \
        _Pragma("unroll")                                                      \
        for (int mt = 0; mt < 2; ++mt)                                         \
            _Pragma("unroll")                                                  \
            for (int nt = 0; nt < 4; ++nt)                                     \
                acc[mt][nt] = __builtin_amdgcn_mfma_f32_16x16x32_bf16(Al[mt], BH[nt], acc[mt][nt], 0, 0, 0); \
        _Pragma("unroll")                                                      \
        for (int mt = 0; mt < 2; ++mt)                                         \
            _Pragma("unroll")                                                  \
            for (int nt = 0; nt < 4; ++nt)                                     \
                acc[mt][nt] = __builtin_amdgcn_mfma_f32_16x16x32_bf16(Ah[mt], BL[nt], acc[mt][nt], 0, 0, 0); \
    }

template <bool PLANES>
__global__ __launch_bounds__(256, 2) void vq_main(
    const float* __restrict__ x, const float* __restrict__ cb,
    const unsigned short* __restrict__ cbh, const unsigned short* __restrict__ cbl,
    const float* __restrict__ e2, float* __restrict__ zq, float* __restrict__ idxf,
    int K) {

    __shared__ char smem[65536];
    short* sXh = (short*)smem;             // [64][256] bf16 hi, granule-swizzled
    short* sXl = (short*)(smem + 32768);   // [64][256] bf16 lo

    const int tid = threadIdx.x;
    const int lane = tid & 63;
    const int w = tid >> 6;          // wave id 0..3
    const int ln = lane & 15;        // column-within-16 (code select)
    const int q = lane >> 4;         // k-octet / point-quad select
    const int wm = (w & 1) * 32;     // wave point-offset (2 point-halves)
    const int wn = (w >> 1) * 64;    // wave code-offset in KT tile (2 code-halves)
    const size_t basep = (size_t)blockIdx.x * BM;

    // ---- split the x tile into LDS once (XOR-swizzled 16B granules) ----
#pragma unroll 1
    for (int j = 0; j < 8; ++j) {
        int gi = j * 256 + tid;        // granule id: 64 rows x 32 granules
        int p = gi >> 5, g = gi & 31;
        const float4* src = (const float4*)(x + (basep + p) * C_DIM + g * 8);
        float4 a0 = src[0], a1 = src[1];
        short8 hi, lo;
#pragma unroll
        for (int i = 0; i < 8; ++i) {
            float f = (i < 4) ? ((const float*)&a0)[i] : ((const float*)&a1)[i - 4];
            unsigned short hh = f2bf(f);
            hi[i] = (short)hh;
            lo[i] = (short)f2bf(f - __uint_as_float((unsigned)hh << 16));
        }
        int dst = p * C_DIM + ((g ^ (p & 31)) * 8);
        *(short8*)(sXh + dst) = hi;
        *(short8*)(sXl + dst) = lo;
    }
    __syncthreads();

    int arow[2], swA[2];
#pragma unroll
    for (int mt = 0; mt < 2; ++mt) {
        int R = wm + mt * 16 + ln;
        arow[mt] = R * C_DIM;
        swA[mt] = R & 31;
    }

    // per-lane top-2 state for 8 point-slots (s = mt*4 + r)
    float d1s[8], d2s[8];
    int c1s[8], c2s[8];
#pragma unroll
    for (int s = 0; s < 8; ++s) { d1s[s] = 1e30f; d2s[s] = 1e30f; c1s[s] = 0; c2s[s] = 1; }

    const int nkt = K / KT;
#pragma unroll 1
    for (int kt = 0; kt < nkt; ++kt) {
        f32x4 acc[2][4];
#pragma unroll
        for (int mt = 0; mt < 2; ++mt)
#pragma unroll
            for (int nt = 0; nt < 4; ++nt)
#pragma unroll
                for (int r = 0; r < 4; ++r) acc[mt][nt][r] = 0.0f;

        int cnv[4];
        float e2v[4];
#pragma unroll
        for (int nt = 0; nt < 4; ++nt) {
            cnv[nt] = kt * KT + wn + nt * 16 + ln;
            e2v[nt] = e2[cnv[nt]];
        }

        const unsigned short* bhp = cbh + ((size_t)kt * KT + wn + ln) * C_DIM + q * 8;
        const unsigned short* blp = cbl + ((size_t)kt * KT + wn + ln) * C_DIM + q * 8;
        const float* cbf = cb + ((size_t)kt * KT + wn + ln) * C_DIM + q * 8;
        (void)cbf;

        short8 B0h[4], B0l[4], B1h[4], B1l[4];
        LOADB(B0h, B0l, 0)
#pragma unroll 1
        for (int ksp = 0; ksp < 4; ++ksp) {
            const int k0 = ksp * 2;
            short8 Ah[2], Al[2];
            // half 1: prefetch B1(k0+1), compute with B0(k0)
            LOADB(B1h, B1l, k0 + 1)
            LOADA(k0)
            MFMA3(B0h, B0l)
            // half 2: prefetch B0(k0+2), compute with B1(k0+1)
            if (ksp < 3) LOADB(B0h, B0l, k0 + 2)
            LOADA(k0 + 1)
            MFMA3(B1h, B1l)
        }

        // ---- per-kt top-2 update (branchless) ----
#pragma unroll
        for (int mt = 0; mt < 2; ++mt)
#pragma unroll
            for (int nt = 0; nt < 4; ++nt)
#pragma unroll
                for (int r = 0; r < 4; ++r) {
                    float d = fmaf(-2.0f, acc[mt][nt][r], e2v[nt]);
                    int s = mt * 4 + r;
                    int cn = cnv[nt];
                    bool lt2 = d < d2s[s];
                    bool lt1 = d < d1s[s];
                    float td = lt1 ? d1s[s] : d;
                    int tc = lt1 ? c1s[s] : cn;
                    d2s[s] = lt2 ? td : d2s[s];
                    c2s[s] = lt2 ? tc : c2s[s];
                    d1s[s] = lt1 ? d : d1s[s];
                    c1s[s] = lt1 ? cn : c1s[s];
                }
    }

    // ---- butterfly top-2 merge across the 16 ln-lanes (codes disjoint) ----
#pragma unroll
    for (int m = 1; m <= 8; m <<= 1) {
#pragma unroll
        for (int s = 0; s < 8; ++s) {
            float od1 = __shfl_xor(d1s[s], m);
            int oc1 = __shfl_xor(c1s[s], m);
            float od2 = __shfl_xor(d2s[s], m);
            int oc2 = __shfl_xor(c2s[s], m);
            bool t = (od1 < d1s[s]) || (od1 == d1s[s] && oc1 < c1s[s]);
            float hd = t ? d1s[s] : od1;   // loser of firsts
            int hc = t ? c1s[s] : oc1;
            float nd1 = t ? od1 : d1s[s];
            int nc1 = t ? oc1 : c1s[s];
            bool u = od2 < d2s[s];
            float md = u ? od2 : d2s[s];   // min of seconds
            int mc = u ? oc2 : c2s[s];
            bool v2 = (hd < md) || (hd == md && hc < mc);
            d2s[s] = v2 ? hd : md;
            c2s[s] = v2 ? hc : mc;
            d1s[s] = nd1;
            c1s[s] = nc1;
        }
    }

    __syncthreads();   // all LDS x-tile reads done; safe to reuse
    float* mD1 = (float*)smem;              // [64][2]
    int* mC1 = (int*)(smem + 512);
    float* mD2 = (float*)(smem + 1024);
    int* mC2 = (int*)(smem + 1536);
    int* sCand = (int*)(smem + 2048);       // [64][2]
    int* sWin = (int*)(smem + 2560);        // [64]

    if (ln == 0) {
        int half = w >> 1;
#pragma unroll
        for (int mt = 0; mt < 2; ++mt)
#pragma unroll
            for (int r = 0; r < 4; ++r) {
                int s = mt * 4 + r;
                int p = wm + mt * 16 + q * 4 + r;
                mD1[p * 2 + half] = d1s[s];
                mC1[p * 2 + half] = c1s[s];
                mD2[p * 2 + half] = d2s[s];
                mC2[p * 2 + half] = c2s[s];
            }
    }
    __syncthreads();

    // ---- per-point merge of the two code-halves -> 2 candidates ----
    if (tid < BM) {
        float da1 = mD1[tid * 2], db1 = mD1[tid * 2 + 1];
        int ca1 = mC1[tid * 2], cb1i = mC1[tid * 2 + 1];
        float da2 = mD2[tid * 2], db2 = mD2[tid * 2 + 1];
        int ca2 = mC2[tid * 2], cb2i = mC2[tid * 2 + 1];
        bool t = (db1 < da1) || (db1 == da1 && cb1i < ca1);
        int c1f = t ? cb1i : ca1;
        float xd1 = t ? db2 : da2;
        int xc1 = t ? cb2i : ca2;
        float xd2 = t ? da1 : db1;
        int xc2 = t ? ca1 : cb1i;
        bool u = (xd1 < xd2) || (xd1 == xd2 && xc1 < xc2);
        int c2f = u ? xc1 : xc2;
        sCand[tid * 2] = c1f;
        sCand[tid * 2 + 1] = c2f;
    }
    __syncthreads();

    // ---- exact fp32 recheck: one thread per (point, candidate) ----
    if (tid < 2 * BM) {
        int p = tid >> 1;
        int cc = sCand[tid];
        const float4* xr4 = (const float4*)(x + (basep + p) * C_DIM);
        const float4* cr4 = (const float4*)(cb + (size_t)cc * C_DIM);
        float4 s4 = {0.f, 0.f, 0.f, 0.f};
#pragma unroll 8
        for (int j = 0; j < 64; ++j) {
            float4 a = xr4[j], b = cr4[j];
            s4.x = fmaf(a.x, b.x, s4.x);
            s4.y = fmaf(a.y, b.y, s4.y);
            s4.z = fmaf(a.z, b.z, s4.z);
            s4.w = fmaf(a.w, b.w, s4.w);
        }
        float dot = (s4.x + s4.y) + (s4.z + s4.w);
        float d = fmaf(-2.0f, dot, e2[cc]);
        float od = __shfl_xor(d, 1);
        int oc = __shfl_xor(cc, 1);
        int winc = (d < od || (d == od && cc < oc)) ? cc : oc;
        if ((tid & 1) == 0) {
            sWin[p] = winc;
            idxf[basep + p] = (float)winc;
        }
    }
    __syncthreads();

    // ---- gather winning codebook rows -> zq (cb is L2-hot) ----
#pragma unroll 2
    for (int p = w * 16; p < w * 16 + 16; ++p) {
        int cc = sWin[p];
        float4 v = ((const float4*)(cb + (size_t)cc * C_DIM))[lane];
        ((float4*)(zq + (basep + p) * C_DIM))[lane] = v;
    }
}

extern "C" void kernel_launch(void* const* d_in, const int* in_sizes, int n_in,
                              void* d_out, int out_size, void* d_ws, size_t ws_size,
                              hipStream_t stream) {
    const float* x = (const float*)d_in[0];
    const float* cb = (const float*)d_in[1];
    int N = in_sizes[0] / C_DIM;   // 131072
    int K = in_sizes[1] / C_DIM;   // 1024

    float* zq = (float*)d_out;
    float* idxf = zq + (size_t)N * C_DIM;

    // workspace: e2 (4 KiB, always) + cbh/cbl planes (1 MiB, only if it fits)
    float* e2 = (float*)d_ws;
    unsigned short* cbh = (unsigned short*)((char*)d_ws + 4096);
    unsigned short* cbl = cbh + (size_t)K * C_DIM;
    size_t need = 4096 + (size_t)K * C_DIM * 2 * sizeof(unsigned short);

    if (ws_size >= need) {
        vq_prep<true><<<dim3((K + 3) / 4), dim3(256), 0, stream>>>(cb, cbh, cbl, e2, K);
        vq_main<true><<<dim3(N / BM), dim3(256), 0, stream>>>(x, cb, cbh, cbl, e2, zq, idxf, K);
    } else {
        vq_prep<false><<<dim3((K + 3) / 4), dim3(256), 0, stream>>>(cb, cbh, cbl, e2, K);
        vq_main<false><<<dim3(N / BM), dim3(256), 0, stream>>>(x, cb, cbh, cbl, e2, zq, idxf, K);
    }
}

// Round 5
// 710.317 us; speedup vs baseline: 1.3644x; 1.0026x over previous
//
#include <hip/hip_runtime.h>
#include <math.h>

// VQ nearest-codebook, v6: sched_barrier-pinned prefetch (anti-sink fix).
//
// History: v1 754 / v3 697 / v4 855 / v5 592 us. All pipes ~10-15% in every
// variant. v5's diagnostic: VGPR=88 despite 64 regs of declared B buffers =>
// compiler SANK each load to just before its consuming MFMA (min-liveness
// schedule), so load->use distance ~2 MFMAs and every L2 load exposes
// ~300-500 cyc. 16 loads/ksp ~= the measured 9K-cyc/ksp stall gap.
//
// v6 = v5 + __builtin_amdgcn_sched_barrier(0) fences: each ks-half issues
// the NEXT half's 8 B global-loads + 4 A ds_reads, then a sched fence, then
// the 24-MFMA cluster consuming the PREVIOUS half's named buffers (A0/A1,
// B0/B1 - all compile-time identified). Loads can't sink past the fence =>
// both buffers stay live (VGPR should rise to ~180-210) and every load gets
// a full MFMA cluster (~470-930 cyc) of latency cover. No s_barrier in the
// loop, so compiler emits counted vmcnt (no drain).
//
// Unchanged (proven): BM=64 / 2048 blocks (planes L2-resident, FETCH 170MB),
// A hi/lo split once into XOR-swizzled LDS (conflicts == 0), 3-pass split
// MFMA per-cell order (hh,lh,hl per ks) => bit-identical distances =>
// top-2 + exact fp32 recheck => absmax 0.

typedef __attribute__((ext_vector_type(8))) short short8;   // 8 bf16 = 4 VGPR
typedef __attribute__((ext_vector_type(4))) float f32x4;

#define C_DIM 256
#define BM 64     // points per block
#define KT 128    // codes per kt tile (8 tiles cover K=1024)

__device__ __forceinline__ unsigned short f2bf(float f) {
    unsigned u = __float_as_uint(f);
    return (unsigned short)((u + 0x7fffu + ((u >> 16) & 1u)) >> 16);
}

// cb (K x 256 fp32) -> exact e2, and (if PLANES) bf16 hi/lo planes.
template <bool PLANES>
__global__ __launch_bounds__(256) void vq_prep(
    const float* __restrict__ cb, unsigned short* __restrict__ cbh,
    unsigned short* __restrict__ cbl, float* __restrict__ e2, int K) {
    int wave = threadIdx.x >> 6;
    int lane = threadIdx.x & 63;
    int code = blockIdx.x * 4 + wave;
    if (code >= K) return;
    float4 v = ((const float4*)(cb + (size_t)code * C_DIM))[lane];
    if constexpr (PLANES) {
        unsigned short h[4], l[4];
#pragma unroll
        for (int i = 0; i < 4; ++i) {
            float f = ((const float*)&v)[i];
            unsigned short hh = f2bf(f);
            h[i] = hh;
            l[i] = f2bf(f - __uint_as_float((unsigned)hh << 16));
        }
        *(ushort4*)(cbh + (size_t)code * C_DIM + lane * 4) = make_ushort4(h[0], h[1], h[2], h[3]);
        *(ushort4*)(cbl + (size_t)code * C_DIM + lane * 4) = make_ushort4(l[0], l[1], l[2], l[3]);
    }
    float s = v.x * v.x + v.y * v.y + v.z * v.z + v.w * v.w;
#pragma unroll
    for (int off = 32; off > 0; off >>= 1) s += __shfl_down(s, off, 64);
    if (lane == 0) e2[code] = s;
}

// A fragments (2 m-tiles) from swizzled LDS into named bufs AH/AL, k-step KS.
#define LOADA(AH, AL, KS)                                            \
    {                                                                \
        const int o_ = (KS) * 4 + q;                                 \
        _Pragma("unroll")                                            \
        for (int mt = 0; mt < 2; ++mt) {                             \
            const int ga_ = ((o_ ^ swA[mt]) * 8);                    \
            AH[mt] = *(const short8*)(sXh + arow[mt] + ga_);         \
            AL[mt] = *(const short8*)(sXl + arow[mt] + ga_);         \
        }                                                            \
    }

// B fragments into named buffers DH/DL (compile-time identity), k-step KS.
#define LOADB(DH, DL, KS)                                                      \
    {                                                                          \
        _Pragma("unroll")                                                      \
        for (int nt = 0; nt < 4; ++nt) {                                       \
            if constexpr (PLANES) {                                            \
                DH[nt] = *(const short8*)(bhp + nt * 16 * C_DIM + (KS) * 32);  \
                DL[nt] = *(const short8*)(blp + nt * 16 * C_DIM + (KS) * 32);  \
            } else {                                                           \
                const float* cp_ = cbf + (size_t)nt * 16 * C_DIM + (KS) * 32;  \
                float4 b0_ = ((const float4*)cp_)[0];                          \
                float4 b1_ = ((const float4*)cp_)[1];                          \
                short8 bh_, bl_;                                               \
                _Pragma("unroll")                                              \
                for (int i = 0; i < 8; ++i) {                                  \
                    float f_ = (i < 4) ? ((const float*)&b0_)[i]               \
                                       : ((const float*)&b1_)[i - 4];          \
                    unsigned short hh_ = f2bf(f_);                             \
                    bh_[i] = (short)hh_;                                       \
                    bl_[i] = (short)f2bf(f_ - __uint_as_float((unsigned)hh_ << 16)); \
                }                                                              \
                DH[nt] = bh_;                                                  \
                DL[nt] = bl_;                                                  \
            }                                                                  \
        }                                                                      \
    }

// 3-pass MFMA cluster on (AH,AL) x (BH,BL).
#define MFMA3(AH, AL, BH, BL)                                                  \
    {                                                                          \
        _Pragma("unroll")                                                      \
        for (int mt = 0; mt < 2; ++mt)                                         \
            _Pragma("unroll")                                                  \
            for (int nt = 0; nt < 4; ++nt)                                     \
                acc[mt][nt] = __builtin_amdgcn_mfma_f32_16x16x32_bf16(AH[mt], BH[nt], acc[mt][nt], 0, 0, 0); \
        _Pragma("unroll")                                                      \
        for (int mt = 0; mt < 2; ++mt)                                         \
            _Pragma("unroll")                                                  \
            for (int nt = 0; nt < 4; ++nt)                                     \
                acc[mt][nt] = __builtin_amdgcn_mfma_f32_16x16x32_bf16(AL[mt], BH[nt], acc[mt][nt], 0, 0, 0); \
        _Pragma("unroll")                                                      \
        for (int mt = 0; mt < 2; ++mt)                                         \
            _Pragma("unroll")                                                  \
            for (int nt = 0; nt < 4; ++nt)                                     \
                acc[mt][nt] = __builtin_amdgcn_mfma_f32_16x16x32_bf16(AH[mt], BL[nt], acc[mt][nt], 0, 0, 0); \
    }

template <bool PLANES>
__global__ __launch_bounds__(256, 2) void vq_main(
    const float* __restrict__ x, const float* __restrict__ cb,
    const unsigned short* __restrict__ cbh, const unsigned short* __restrict__ cbl,
    const float* __restrict__ e2, float* __restrict__ zq, float* __restrict__ idxf,
    int K) {

    __shared__ char smem[65536];
    short* sXh = (short*)smem;             // [64][256] bf16 hi, granule-swizzled
    short* sXl = (short*)(smem + 32768);   // [64][256] bf16 lo

    const int tid = threadIdx.x;
    const int lane = tid & 63;
    const int w = tid >> 6;          // wave id 0..3
    const int ln = lane & 15;        // column-within-16 (code select)
    const int q = lane >> 4;         // k-octet / point-quad select
    const int wm = (w & 1) * 32;     // wave point-offset (2 point-halves)
    const int wn = (w >> 1) * 64;    // wave code-offset in KT tile (2 code-halves)
    const size_t basep = (size_t)blockIdx.x * BM;

    // ---- split the x tile into LDS once (XOR-swizzled 16B granules) ----
#pragma unroll 1
    for (int j = 0; j < 8; ++j) {
        int gi = j * 256 + tid;        // granule id: 64 rows x 32 granules
        int p = gi >> 5, g = gi & 31;
        const float4* src = (const float4*)(x + (basep + p) * C_DIM + g * 8);
        float4 a0 = src[0], a1 = src[1];
        short8 hi, lo;
#pragma unroll
        for (int i = 0; i < 8; ++i) {
            float f = (i < 4) ? ((const float*)&a0)[i] : ((const float*)&a1)[i - 4];
            unsigned short hh = f2bf(f);
            hi[i] = (short)hh;
            lo[i] = (short)f2bf(f - __uint_as_float((unsigned)hh << 16));
        }
        int dst = p * C_DIM + ((g ^ (p & 31)) * 8);
        *(short8*)(sXh + dst) = hi;
        *(short8*)(sXl + dst) = lo;
    }
    __syncthreads();

    int arow[2], swA[2];
#pragma unroll
    for (int mt = 0; mt < 2; ++mt) {
        int R = wm + mt * 16 + ln;
        arow[mt] = R * C_DIM;
        swA[mt] = R & 31;
    }

    // per-lane top-2 state for 8 point-slots (s = mt*4 + r)
    float d1s[8], d2s[8];
    int c1s[8], c2s[8];
#pragma unroll
    for (int s = 0; s < 8; ++s) { d1s[s] = 1e30f; d2s[s] = 1e30f; c1s[s] = 0; c2s[s] = 1; }

    const int nkt = K / KT;
#pragma unroll 1
    for (int kt = 0; kt < nkt; ++kt) {
        f32x4 acc[2][4];
#pragma unroll
        for (int mt = 0; mt < 2; ++mt)
#pragma unroll
            for (int nt = 0; nt < 4; ++nt)
#pragma unroll
                for (int r = 0; r < 4; ++r) acc[mt][nt][r] = 0.0f;

        int cnv[4];
        float e2v[4];
#pragma unroll
        for (int nt = 0; nt < 4; ++nt) {
            cnv[nt] = kt * KT + wn + nt * 16 + ln;
            e2v[nt] = e2[cnv[nt]];
        }

        const unsigned short* bhp = cbh + ((size_t)kt * KT + wn + ln) * C_DIM + q * 8;
        const unsigned short* blp = cbl + ((size_t)kt * KT + wn + ln) * C_DIM + q * 8;
        const float* cbf = cb + ((size_t)kt * KT + wn + ln) * C_DIM + q * 8;
        (void)cbf;

        short8 B0h[4], B0l[4], B1h[4], B1l[4];
        short8 A0h[2], A0l[2], A1h[2], A1l[2];
        LOADB(B0h, B0l, 0)
        LOADA(A0h, A0l, 0)
#pragma unroll 1
        for (int ksp = 0; ksp < 4; ++ksp) {
            const int k0 = ksp * 2;
            // half 1: issue prefetch of ks=k0+1, fence, compute ks=k0.
            LOADB(B1h, B1l, k0 + 1)
            LOADA(A1h, A1l, k0 + 1)
            __builtin_amdgcn_sched_barrier(0);   // loads may not sink below
            MFMA3(A0h, A0l, B0h, B0l)
            // half 2: issue prefetch of ks=k0+2, fence, compute ks=k0+1.
            if (ksp < 3) {
                LOADB(B0h, B0l, k0 + 2)
                LOADA(A0h, A0l, k0 + 2)
            }
            __builtin_amdgcn_sched_barrier(0);
            MFMA3(A1h, A1l, B1h, B1l)
        }

        // ---- per-kt top-2 update (branchless) ----
#pragma unroll
        for (int mt = 0; mt < 2; ++mt)
#pragma unroll
            for (int nt = 0; nt < 4; ++nt)
#pragma unroll
                for (int r = 0; r < 4; ++r) {
                    float d = fmaf(-2.0f, acc[mt][nt][r], e2v[nt]);
                    int s = mt * 4 + r;
                    int cn = cnv[nt];
                    bool lt2 = d < d2s[s];
                    bool lt1 = d < d1s[s];
                    float td = lt1 ? d1s[s] : d;
                    int tc = lt1 ? c1s[s] : cn;
                    d2s[s] = lt2 ? td : d2s[s];
                    c2s[s] = lt2 ? tc : c2s[s];
                    d1s[s] = lt1 ? d : d1s[s];
                    c1s[s] = lt1 ? cn : c1s[s];
                }
    }

    // ---- butterfly top-2 merge across the 16 ln-lanes (codes disjoint) ----
#pragma unroll
    for (int m = 1; m <= 8; m <<= 1) {
#pragma unroll
        for (int s = 0; s < 8; ++s) {
            float od1 = __shfl_xor(d1s[s], m);
            int oc1 = __shfl_xor(c1s[s], m);
            float od2 = __shfl_xor(d2s[s], m);
            int oc2 = __shfl_xor(c2s[s], m);
            bool t = (od1 < d1s[s]) || (od1 == d1s[s] && oc1 < c1s[s]);
            float hd = t ? d1s[s] : od1;   // loser of firsts
            int hc = t ? c1s[s] : oc1;
            float nd1 = t ? od1 : d1s[s];
            int nc1 = t ? oc1 : c1s[s];
            bool u = od2 < d2s[s];
            float md = u ? od2 : d2s[s];   // min of seconds
            int mc = u ? oc2 : c2s[s];
            bool v2 = (hd < md) || (hd == md && hc < mc);
            d2s[s] = v2 ? hd : md;
            c2s[s] = v2 ? hc : mc;
            d1s[s] = nd1;
            c1s[s] = nc1;
        }
    }

    __syncthreads();   // all LDS x-tile reads done; safe to reuse
    float* mD1 = (float*)smem;              // [64][2]
    int* mC1 = (int*)(smem + 512);
    float* mD2 = (float*)(smem + 1024);
    int* mC2 = (int*)(smem + 1536);
    int* sCand = (int*)(smem + 2048);       // [64][2]
    int* sWin = (int*)(smem + 2560);        // [64]

    if (ln == 0) {
        int half = w >> 1;
#pragma unroll
        for (int mt = 0; mt < 2; ++mt)
#pragma unroll
            for (int r = 0; r < 4; ++r) {
                int s = mt * 4 + r;
                int p = wm + mt * 16 + q * 4 + r;
                mD1[p * 2 + half] = d1s[s];
                mC1[p * 2 + half] = c1s[s];
                mD2[p * 2 + half] = d2s[s];
                mC2[p * 2 + half] = c2s[s];
            }
    }
    __syncthreads();

    // ---- per-point merge of the two code-halves -> 2 candidates ----
    if (tid < BM) {
        float da1 = mD1[tid * 2], db1 = mD1[tid * 2 + 1];
        int ca1 = mC1[tid * 2], cb1i = mC1[tid * 2 + 1];
        float da2 = mD2[tid * 2], db2 = mD2[tid * 2 + 1];
        int ca2 = mC2[tid * 2], cb2i = mC2[tid * 2 + 1];
        bool t = (db1 < da1) || (db1 == da1 && cb1i < ca1);
        int c1f = t ? cb1i : ca1;
        float xd1 = t ? db2 : da2;
        int xc1 = t ? cb2i : ca2;
        float xd2 = t ? da1 : db1;
        int xc2 = t ? ca1 : cb1i;
        bool u = (xd1 < xd2) || (xd1 == xd2 && xc1 < xc2);
        int c2f = u ? xc1 : xc2;
        sCand[tid * 2] = c1f;
        sCand[tid * 2 + 1] = c2f;
    }
    __syncthreads();

    // ---- exact fp32 recheck: one thread per (point, candidate) ----
    if (tid < 2 * BM) {
        int p = tid >> 1;
        int cc = sCand[tid];
        const float4* xr4 = (const float4*)(x + (basep + p) * C_DIM);
        const float4* cr4 = (const float4*)(cb + (size_t)cc * C_DIM);
        float4 s4 = {0.f, 0.f, 0.f, 0.f};
#pragma unroll 8
        for (int j = 0; j < 64; ++j) {
            float4 a = xr4[j], b = cr4[j];
            s4.x = fmaf(a.x, b.x, s4.x);
            s4.y = fmaf(a.y, b.y, s4.y);
            s4.z = fmaf(a.z, b.z, s4.z);
            s4.w = fmaf(a.w, b.w, s4.w);
        }
        float dot = (s4.x + s4.y) + (s4.z + s4.w);
        float d = fmaf(-2.0f, dot, e2[cc]);
        float od = __shfl_xor(d, 1);
        int oc = __shfl_xor(cc, 1);
        int winc = (d < od || (d == od && cc < oc)) ? cc : oc;
        if ((tid & 1) == 0) {
            sWin[p] = winc;
            idxf[basep + p] = (float)winc;
        }
    }
    __syncthreads();

    // ---- gather winning codebook rows -> zq (cb is L2-hot) ----
#pragma unroll 2
    for (int p = w * 16; p < w * 16 + 16; ++p) {
        int cc = sWin[p];
        float4 v = ((const float4*)(cb + (size_t)cc * C_DIM))[lane];
        ((float4*)(zq + (basep + p) * C_DIM))[lane] = v;
    }
}

extern "C" void kernel_launch(void* const* d_in, const int* in_sizes, int n_in,
                              void* d_out, int out_size, void* d_ws, size_t ws_size,
                              hipStream_t stream) {
    const float* x = (const float*)d_in[0];
    const float* cb = (const float*)d_in[1];
    int N = in_sizes[0] / C_DIM;   // 131072
    int K = in_sizes[1] / C_DIM;   // 1024

    float* zq = (float*)d_out;
    float* idxf = zq + (size_t)N * C_DIM;

    // workspace: e2 (4 KiB, always) + cbh/cbl planes (1 MiB, only if it fits)
    float* e2 = (float*)d_ws;
    unsigned short* cbh = (unsigned short*)((char*)d_ws + 4096);
    unsigned short* cbl = cbh + (size_t)K * C_DIM;
    size_t need = 4096 + (size_t)K * C_DIM * 2 * sizeof(unsigned short);

    if (ws_size >= need) {
        vq_prep<true><<<dim3((K + 3) / 4), dim3(256), 0, stream>>>(cb, cbh, cbl, e2, K);
        vq_main<true><<<dim3(N / BM), dim3(256), 0, stream>>>(x, cb, cbh, cbl, e2, zq, idxf, K);
    } else {
        vq_prep<false><<<dim3((K + 3) / 4), dim3(256), 0, stream>>>(cb, cbh, cbl, e2, K);
        vq_main<false><<<dim3(N / BM), dim3(256), 0, stream>>>(x, cb, cbh, cbl, e2, zq, idxf, K);
    }
}